// Round 9
// baseline (407.318 us; speedup 1.0000x reference)
//
#include <hip/hip_runtime.h>
#include <hip/hip_bf16.h>
#include <math.h>

#define N_VOTERS 1048576
#define NUM_CAND 32
#define EMB 128
#define NUM_ELEC 4096

typedef unsigned short u16;
typedef unsigned int u32;
typedef __attribute__((ext_vector_type(8))) short bf16x8;
typedef __attribute__((ext_vector_type(4))) short short4v;
typedef __attribute__((ext_vector_type(4))) float f32x4;

__device__ __forceinline__ u16 f2bf(float f) {   // RNE (prep only)
    union { float f; u32 u; } v; v.f = f;
    u32 r = v.u + 0x7FFFu + ((v.u >> 16) & 1u);
    return (u16)(r >> 16);
}
// pack two floats to bf16 (round-half-up): f0 -> low16, f1 -> high16
__device__ __forceinline__ u32 pkbf(float f0, float f1) {
    u32 u0 = __float_as_uint(f0) + 0x8000u;
    u32 u1 = __float_as_uint(f1) + 0x8000u;
    return __builtin_amdgcn_perm(u1, u0, 0x07060302u);
}

// ---------------- Kernel A: transpose+convert local weights to bf16 ----------------
// w1t: [128][32] = W1^T (out-major); w2t/w3t: [128][128] (out-major) — A-frag layout.
__global__ void prep_weights(const float* __restrict__ lW1, const float* __restrict__ lW2,
                             const float* __restrict__ lW3,
                             u16* __restrict__ w1t, u16* __restrict__ w2t, u16* __restrict__ w3t) {
    int tid = blockIdx.x * blockDim.x + threadIdx.x;  // 0..16383
    if (tid < 4096) {
        int n = tid >> 5, k = tid & 31;
        w1t[tid] = f2bf(lW1[k * EMB + n]);
    }
    {
        int n = tid >> 7, k = tid & 127;
        w2t[tid] = f2bf(lW2[k * EMB + n]);
        w3t[tid] = f2bf(lW3[k * EMB + n]);
    }
}

// ---------------- Kernel B: fused local MLP, grid-stride groups, resident weights -------
// 2048 blocks x 256 thr (4 waves). Wave wv owns features wv*32..+31 (2 m-tiles); weights +
// biases loaded ONCE per block into VGPRs. 8 groups x 64 voters per block: per group, x is
// prefetched (packed bf16) one group ahead in registers, staged via bufX, then
// L1 -> act1 -> L2 -> act2 -> L3 with 3 barriers. Bias1/2 ride the MFMA C operand.
// Layer-3 C-operand chains the segment sum across subtiles AND groups; flush = butterfly
// over 16 voter lanes + l15==0 atomics. Bias3 deferred via per-election voter counts.
// launch_bounds(256,4): LDS 39424*4 = 157,696 <= 160 KiB -> 4 blocks/CU (50% cap);
// R8 measured 84 VGPR so the 128-cap is safe (spill tripwire: WRITE_SIZE explosion).
__global__ __launch_bounds__(256, 4) void local_fused(
    const float* __restrict__ x, const int* __restrict__ idx,
    const float* __restrict__ lb1, const float* __restrict__ lb2,
    const u16* __restrict__ w1t, const u16* __restrict__ w2t, const u16* __restrict__ w3t,
    float* __restrict__ agg, float* __restrict__ cntf)
{
    constexpr int XSTR = 36;   // x tile stride (72B rows, 8B-aligned b64 reads)
    constexpr int ASTR = 136;  // act stride (272B rows, 16B-aligned b128 reads)
    __shared__ __align__(16) u16 bufX[64 * XSTR];   //  4608 B
    __shared__ __align__(16) u16 act1[64 * ASTR];   // 17408 B
    __shared__ __align__(16) u16 act2[64 * ASTR];   // 17408 B  (total 39424)

    const int tid = threadIdx.x;
    const int lane = tid & 63;
    const int wv = tid >> 6;        // feature quarter 0..3
    const int qd = lane >> 4;
    const int l15 = lane & 15;
    const int f0 = wv * 32;
    const int vbase = blockIdx.x * 512;

    // ---- weights + biases resident for the whole block ----
    bf16x8 w1a[2], w2a[2][4], w3a[2][4];
    f32x4 b1f[2], b2f[2];
    #pragma unroll
    for (int mt = 0; mt < 2; ++mt) {
        int mrow = f0 + mt * 16 + l15;
        w1a[mt] = *(const bf16x8*)(w1t + mrow * 32 + qd * 8);
        #pragma unroll
        for (int kk = 0; kk < 4; ++kk) {
            w2a[mt][kk] = *(const bf16x8*)(w2t + mrow * 128 + kk * 32 + qd * 8);
            w3a[mt][kk] = *(const bf16x8*)(w3t + mrow * 128 + kk * 32 + qd * 8);
        }
        b1f[mt] = *(const f32x4*)(lb1 + f0 + mt * 16 + qd * 4);
        b2f[mt] = *(const f32x4*)(lb2 + f0 + mt * 16 + qd * 4);
    }

    // ---- segment state (spans all 8 groups) ----
    f32x4 accR[2];
    #pragma unroll
    for (int mt = 0; mt < 2; ++mt) accR[mt] = (f32x4){0.f, 0.f, 0.f, 0.f};
    float cntv = 0.f;
    int cur = idx[vbase];

    auto flush = [&]() {   // wave-uniform call sites only
        #pragma unroll
        for (int d = 1; d < 16; d <<= 1)
            #pragma unroll
            for (int mt = 0; mt < 2; ++mt)
                #pragma unroll
                for (int r = 0; r < 4; ++r) accR[mt][r] += __shfl_xor(accR[mt][r], d, 16);
        if (l15 == 0) {
            float* p = agg + (size_t)cur * EMB + f0 + qd * 4;
            #pragma unroll
            for (int mt = 0; mt < 2; ++mt)
                #pragma unroll
                for (int r = 0; r < 4; ++r) atomicAdd(p + mt * 16 + r, accR[mt][r]);
            if (wv == 0 && qd == 0) atomicAdd(cntf + cur, cntv);
        }
        #pragma unroll
        for (int mt = 0; mt < 2; ++mt) accR[mt] = (f32x4){0.f, 0.f, 0.f, 0.f};
        cntv = 0.f;
    };

    // ---- prefetch group 0's x tile, packed bf16 in registers ----
    uint2 xp[2];
    {
        const float4* xg = (const float4*)(x + (size_t)vbase * NUM_CAND);
        #pragma unroll
        for (int i = 0; i < 2; ++i) {
            float4 v = xg[i * 256 + tid];
            xp[i].x = pkbf(v.x, v.y); xp[i].y = pkbf(v.z, v.w);
        }
    }

    #pragma unroll 1
    for (int g = 0; g < 8; ++g) {
        const int vg = vbase + g * 64;

        // ---- stage bufX from prefetched regs; prefetch next group ----
        #pragma unroll
        for (int i = 0; i < 2; ++i) {
            int F = i * 256 + tid, row = F >> 3, c4 = (F & 7) * 4;
            *(uint2*)(bufX + row * XSTR + c4) = xp[i];
        }
        if (g < 7) {
            const float4* xg = (const float4*)(x + (size_t)(vg + 64) * NUM_CAND);
            #pragma unroll
            for (int i = 0; i < 2; ++i) {
                float4 v = xg[i * 256 + tid];
                xp[i].x = pkbf(v.x, v.y); xp[i].y = pkbf(v.z, v.w);
            }
        }
        // hoist this group's segment ids (4 independent loads issue together; latency
        // overlaps L1/L2 compute instead of sitting after barrier B_c)
        int sgv[4];
        #pragma unroll
        for (int nt = 0; nt < 4; ++nt) sgv[nt] = idx[vg + nt * 16 + l15];
        __syncthreads();                       // B_a: bufX visible

        // ---- layer 1 (K=32): bufX -> act1, bias in C, relu ----
        #pragma unroll
        for (int nt = 0; nt < 4; ++nt) {
            int vr = nt * 16 + l15;
            union { bf16x8 v; short4v h[2]; } b;
            b.h[0] = *(const short4v*)(bufX + vr * XSTR + qd * 8);
            b.h[1] = *(const short4v*)(bufX + vr * XSTR + qd * 8 + 4);
            u16* wr = act1 + vr * ASTR + f0 + qd * 4;
            #pragma unroll
            for (int mt = 0; mt < 2; ++mt) {
                f32x4 a = __builtin_amdgcn_mfma_f32_16x16x32_bf16(w1a[mt], b.v, b1f[mt], 0, 0, 0);
                uint2 s;
                s.x = pkbf(fmaxf(a[0], 0.f), fmaxf(a[1], 0.f));
                s.y = pkbf(fmaxf(a[2], 0.f), fmaxf(a[3], 0.f));
                *(uint2*)(wr + mt * 16) = s;
            }
        }
        __syncthreads();                       // B_b: act1 visible

        // ---- layer 2 (K=128): act1 -> act2, bias in C, relu ----
        #pragma unroll
        for (int nt = 0; nt < 4; ++nt) {
            const u16* rd = act1 + (nt * 16 + l15) * ASTR + qd * 8;
            bf16x8 B2[4];
            #pragma unroll
            for (int kk = 0; kk < 4; ++kk) B2[kk] = *(const bf16x8*)(rd + kk * 32);
            u16* wr = act2 + (nt * 16 + l15) * ASTR + f0 + qd * 4;
            #pragma unroll
            for (int mt = 0; mt < 2; ++mt) {
                f32x4 a = b2f[mt];
                #pragma unroll
                for (int kk = 0; kk < 4; ++kk)
                    a = __builtin_amdgcn_mfma_f32_16x16x32_bf16(w2a[mt][kk], B2[kk], a, 0, 0, 0);
                uint2 s;
                s.x = pkbf(fmaxf(a[0], 0.f), fmaxf(a[1], 0.f));
                s.y = pkbf(fmaxf(a[2], 0.f), fmaxf(a[3], 0.f));
                *(uint2*)(wr + mt * 16) = s;
            }
        }
        __syncthreads();                       // B_c: act2 visible

        // ---- layer 3 (K=128): act2 -> accR via C-chaining ----
        #pragma unroll 1
        for (int nt = 0; nt < 4; ++nt) {
            int sg = sgv[nt];
            const u16* rd = act2 + (nt * 16 + l15) * ASTR + qd * 8;
            bf16x8 B3[4];
            #pragma unroll
            for (int kk = 0; kk < 4; ++kk) B3[kk] = *(const bf16x8*)(rd + kk * 32);
            int first = __builtin_amdgcn_readfirstlane(sg);
            bool uni = (__ballot(sg == first) == ~0ull);
            if (uni) {
                if (first != cur) {
                    if (cntv > 0.f) flush();
                    cur = first;
                }
                #pragma unroll
                for (int mt = 0; mt < 2; ++mt) {
                    f32x4 a = accR[mt];
                    #pragma unroll
                    for (int kk = 0; kk < 4; ++kk)
                        a = __builtin_amdgcn_mfma_f32_16x16x32_bf16(w3a[mt][kk], B3[kk], a, 0, 0, 0);
                    accR[mt] = a;
                }
                cntv += 16.f;
            } else {                           // boundary inside subtile (rare)
                if (cntv > 0.f) flush();
                f32x4 D[2];
                #pragma unroll
                for (int mt = 0; mt < 2; ++mt) {
                    f32x4 a = {0.f, 0.f, 0.f, 0.f};
                    #pragma unroll
                    for (int kk = 0; kk < 4; ++kk)
                        a = __builtin_amdgcn_mfma_f32_16x16x32_bf16(w3a[mt][kk], B3[kk], a, 0, 0, 0);
                    D[mt] = a;
                }
                // segmented inclusive scan over 16 voter lanes (sorted -> masking safe)
                float one = 1.f;
                #pragma unroll
                for (int d = 1; d < 16; d <<= 1) {
                    int so = __shfl_up(sg, d, 16);
                    bool ok = (l15 >= d) && (so == sg);
                    #pragma unroll
                    for (int mt = 0; mt < 2; ++mt)
                        #pragma unroll
                        for (int r = 0; r < 4; ++r) {
                            float o = __shfl_up(D[mt][r], d, 16);
                            if (ok) D[mt][r] += o;
                        }
                    float oc = __shfl_up(one, d, 16);
                    if (ok) one += oc;
                }
                int sgn = __shfl_down(sg, 1, 16);
                bool isend = (l15 == 15) || (sgn != sg);
                if (isend) {
                    float* p = agg + (size_t)sg * EMB + f0 + qd * 4;
                    #pragma unroll
                    for (int mt = 0; mt < 2; ++mt)
                        #pragma unroll
                        for (int r = 0; r < 4; ++r) atomicAdd(p + mt * 16 + r, D[mt][r]);
                    if (wv == 0 && qd == 0) atomicAdd(cntf + sg, one);
                }
                cur = __shfl(sg, 15, 16);      // last voter's run continues
            }
        }
    }
    if (cntv > 0.f) flush();
}

// ---------------- Kernel C: global MLP + log_softmax (fp32) ----------------
// Adds deferred local bias3: agg_true[s][j] = agg[s][j] + cnt[s]*lb3[j].
__global__ __launch_bounds__(256) void global_mlp(
    const float* __restrict__ agg, const float* __restrict__ cntf, const float* __restrict__ lb3,
    const float* __restrict__ gW1, const float* __restrict__ gb1,
    const float* __restrict__ gW2, const float* __restrict__ gb2,
    const float* __restrict__ gW3, const float* __restrict__ gb3,
    float* __restrict__ out)
{
    __shared__ float actA[8 * 128];
    __shared__ float actB[8 * 128];
    __shared__ float sc[8 * 32];
    const int tid = threadIdx.x;
    const int s0 = blockIdx.x * 8;

    #pragma unroll
    for (int i = 0; i < 4; ++i) {
        int f = i * 256 + tid;
        actA[f] = agg[(size_t)s0 * 128 + f] + cntf[s0 + (f >> 7)] * lb3[f & 127];
    }
    __syncthreads();

    const int j = tid & 127, g = tid >> 7;
    {
        float acc[4];
        #pragma unroll
        for (int si = 0; si < 4; ++si) acc[si] = gb1[j];
        #pragma unroll 8
        for (int k = 0; k < 128; ++k) {
            float w = gW1[k * 128 + j];
            #pragma unroll
            for (int si = 0; si < 4; ++si) acc[si] += actA[(g * 4 + si) * 128 + k] * w;
        }
        #pragma unroll
        for (int si = 0; si < 4; ++si) actB[(g * 4 + si) * 128 + j] = fmaxf(acc[si], 0.f);
    }
    __syncthreads();
    {
        float acc[4];
        #pragma unroll
        for (int si = 0; si < 4; ++si) acc[si] = gb2[j];
        #pragma unroll 8
        for (int k = 0; k < 128; ++k) {
            float w = gW2[k * 128 + j];
            #pragma unroll
            for (int si = 0; si < 4; ++si) acc[si] += actB[(g * 4 + si) * 128 + k] * w;
        }
        #pragma unroll
        for (int si = 0; si < 4; ++si) actA[(g * 4 + si) * 128 + j] = fmaxf(acc[si], 0.f);
    }
    __syncthreads();
    {
        int c = tid & 31, sg = tid >> 5;
        float a3 = gb3[c];
        #pragma unroll 8
        for (int k = 0; k < 128; ++k) a3 += actA[sg * 128 + k] * gW3[k * 32 + c];
        sc[sg * 32 + c] = a3;
    }
    __syncthreads();
    {
        int c = tid & 31, sg = tid >> 5;
        float v = sc[sg * 32 + c];
        float m = v;
        #pragma unroll
        for (int off = 16; off >= 1; off >>= 1) m = fmaxf(m, __shfl_xor(m, off, 32));
        float e = expf(v - m);
        float sum = e;
        #pragma unroll
        for (int off = 16; off >= 1; off >>= 1) sum += __shfl_xor(sum, off, 32);
        out[(size_t)(s0 + sg) * 32 + c] = (v - m) - logf(sum);
    }
}

extern "C" void kernel_launch(void* const* d_in, const int* in_sizes, int n_in,
                              void* d_out, int out_size, void* d_ws, size_t ws_size,
                              hipStream_t stream) {
    const float* x   = (const float*)d_in[0];
    const int*   idx = (const int*)d_in[1];
    const float* lW1 = (const float*)d_in[2];
    const float* lb1 = (const float*)d_in[3];
    const float* lW2 = (const float*)d_in[4];
    const float* lb2 = (const float*)d_in[5];
    const float* lW3 = (const float*)d_in[6];
    const float* lb3 = (const float*)d_in[7];
    const float* gW1 = (const float*)d_in[8];
    const float* gb1 = (const float*)d_in[9];
    const float* gW2 = (const float*)d_in[10];
    const float* gb2 = (const float*)d_in[11];
    const float* gW3 = (const float*)d_in[12];
    const float* gb3 = (const float*)d_in[13];
    float* out = (float*)d_out;

    float* agg  = (float*)d_ws;                                 // [4096][128] fp32 = 2 MB
    float* cntf = agg + (size_t)NUM_ELEC * EMB;                 // [4096] fp32
    u16* w1t = (u16*)(cntf + NUM_ELEC);
    u16* w2t = w1t + 128 * 32;
    u16* w3t = w2t + 128 * 128;

    hipMemsetAsync(d_ws, 0, ((size_t)NUM_ELEC * EMB + NUM_ELEC) * sizeof(float), stream);
    prep_weights<<<64, 256, 0, stream>>>(lW1, lW2, lW3, w1t, w2t, w3t);
    local_fused<<<N_VOTERS / 512, 256, 0, stream>>>(x, idx, lb1, lb2, w1t, w2t, w3t, agg, cntf);
    global_mlp<<<NUM_ELEC / 8, 256, 0, stream>>>(agg, cntf, lb3, gW1, gb1, gW2, gb2, gW3, gb3, out);
}

// Round 10
// 301.312 us; speedup vs baseline: 1.3518x; 1.3518x over previous
//
#include <hip/hip_runtime.h>
#include <hip/hip_bf16.h>
#include <math.h>

#define N_VOTERS 1048576
#define NUM_CAND 32
#define EMB 128
#define NUM_ELEC 4096

typedef unsigned short u16;
typedef unsigned int u32;
typedef __attribute__((ext_vector_type(8))) short bf16x8;
typedef __attribute__((ext_vector_type(4))) short short4v;
typedef __attribute__((ext_vector_type(4))) float f32x4;

__device__ __forceinline__ u16 f2bf(float f) {   // RNE (prep only)
    union { float f; u32 u; } v; v.f = f;
    u32 r = v.u + 0x7FFFu + ((v.u >> 16) & 1u);
    return (u16)(r >> 16);
}
// pack two floats to bf16 (round-half-up): f0 -> low16, f1 -> high16
__device__ __forceinline__ u32 pkbf(float f0, float f1) {
    u32 u0 = __float_as_uint(f0) + 0x8000u;
    u32 u1 = __float_as_uint(f1) + 0x8000u;
    return __builtin_amdgcn_perm(u1, u0, 0x07060302u);
}

// ---------------- Kernel A: transpose+convert local weights to bf16 ----------------
// w1t: [128][32] = W1^T (out-major); w2t/w3t: [128][128] (out-major) — A-frag layout.
__global__ void prep_weights(const float* __restrict__ lW1, const float* __restrict__ lW2,
                             const float* __restrict__ lW3,
                             u16* __restrict__ w1t, u16* __restrict__ w2t, u16* __restrict__ w3t) {
    int tid = blockIdx.x * blockDim.x + threadIdx.x;  // 0..16383
    if (tid < 4096) {
        int n = tid >> 5, k = tid & 31;
        w1t[tid] = f2bf(lW1[k * EMB + n]);
    }
    {
        int n = tid >> 7, k = tid & 127;
        w2t[tid] = f2bf(lW2[k * EMB + n]);
        w3t[tid] = f2bf(lW3[k * EMB + n]);
    }
}

// ---------------- Kernel B: fused local MLP, grid-stride groups, resident weights -------
// 2048 blocks x 256 thr (4 waves). Wave wv owns features wv*32..+31 (2 m-tiles); weights +
// biases loaded ONCE per block into VGPRs (needs the >=160-VGPR budget of
// __launch_bounds__(256,3) — at (256,4) the compiler REMATERIALIZES weight loads per group:
// R9 measured FETCH 68->371 MB, 155->226 us. Do not tighten).
// 8 groups x 64 voters. bufX is DOUBLE-BUFFERED: group g's L2 phase stages bufX for g+1
// from registers prefetched in group g-1, so the act2 barrier also publishes bufX and the
// per-group staging barrier disappears -> 2 barriers/group (17/block vs R8's 24).
// Bias1/2 ride the MFMA C operand. Layer-3 C-operand chains the segment sum across
// subtiles AND groups; flush = butterfly over 16 voter lanes + l15==0 atomics.
// Bias3 deferred to global_mlp via per-election voter counts.
__global__ __launch_bounds__(256, 3) void local_fused(
    const float* __restrict__ x, const int* __restrict__ idx,
    const float* __restrict__ lb1, const float* __restrict__ lb2,
    const u16* __restrict__ w1t, const u16* __restrict__ w2t, const u16* __restrict__ w3t,
    float* __restrict__ agg, float* __restrict__ cntf)
{
    constexpr int XSTR = 36;   // x tile stride (72B rows, 8B-aligned b64 reads)
    constexpr int ASTR = 136;  // act stride (272B rows, 16B-aligned b128 reads)
    __shared__ __align__(16) u16 bufX[2][64 * XSTR];  // 2 x 4608 B
    __shared__ __align__(16) u16 act1[64 * ASTR];     // 17408 B
    __shared__ __align__(16) u16 act2[64 * ASTR];     // 17408 B  (total 44032)

    const int tid = threadIdx.x;
    const int lane = tid & 63;
    const int wv = tid >> 6;        // feature quarter 0..3
    const int qd = lane >> 4;
    const int l15 = lane & 15;
    const int f0 = wv * 32;
    const int vbase = blockIdx.x * 512;

    // ---- weights + biases resident for the whole block ----
    bf16x8 w1a[2], w2a[2][4], w3a[2][4];
    f32x4 b1f[2], b2f[2];
    #pragma unroll
    for (int mt = 0; mt < 2; ++mt) {
        int mrow = f0 + mt * 16 + l15;
        w1a[mt] = *(const bf16x8*)(w1t + mrow * 32 + qd * 8);
        #pragma unroll
        for (int kk = 0; kk < 4; ++kk) {
            w2a[mt][kk] = *(const bf16x8*)(w2t + mrow * 128 + kk * 32 + qd * 8);
            w3a[mt][kk] = *(const bf16x8*)(w3t + mrow * 128 + kk * 32 + qd * 8);
        }
        b1f[mt] = *(const f32x4*)(lb1 + f0 + mt * 16 + qd * 4);
        b2f[mt] = *(const f32x4*)(lb2 + f0 + mt * 16 + qd * 4);
    }

    // ---- segment state (spans all 8 groups) ----
    f32x4 accR[2];
    #pragma unroll
    for (int mt = 0; mt < 2; ++mt) accR[mt] = (f32x4){0.f, 0.f, 0.f, 0.f};
    float cntv = 0.f;
    int cur = idx[vbase];

    auto flush = [&]() {   // wave-uniform call sites only
        #pragma unroll
        for (int d = 1; d < 16; d <<= 1)
            #pragma unroll
            for (int mt = 0; mt < 2; ++mt)
                #pragma unroll
                for (int r = 0; r < 4; ++r) accR[mt][r] += __shfl_xor(accR[mt][r], d, 16);
        if (l15 == 0) {
            float* p = agg + (size_t)cur * EMB + f0 + qd * 4;
            #pragma unroll
            for (int mt = 0; mt < 2; ++mt)
                #pragma unroll
                for (int r = 0; r < 4; ++r) atomicAdd(p + mt * 16 + r, accR[mt][r]);
            if (wv == 0 && qd == 0) atomicAdd(cntf + cur, cntv);
        }
        #pragma unroll
        for (int mt = 0; mt < 2; ++mt) accR[mt] = (f32x4){0.f, 0.f, 0.f, 0.f};
        cntv = 0.f;
    };

    auto loadx = [&](int v0, uint2* xp) {   // coalesced read + pack of one 64-voter tile
        const float4* xg = (const float4*)(x + (size_t)v0 * NUM_CAND);
        #pragma unroll
        for (int i = 0; i < 2; ++i) {
            float4 v = xg[i * 256 + tid];
            xp[i].x = pkbf(v.x, v.y); xp[i].y = pkbf(v.z, v.w);
        }
    };
    auto stagex = [&](u16* dst, const uint2* xp) {
        #pragma unroll
        for (int i = 0; i < 2; ++i) {
            int F = i * 256 + tid, row = F >> 3, c4 = (F & 7) * 4;
            *(uint2*)(dst + row * XSTR + c4) = xp[i];
        }
    };

    // ---- prologue: stage group 0, prefetch group 1 into regs ----
    uint2 xp[2];
    loadx(vbase, xp);
    stagex(bufX[0], xp);
    loadx(vbase + 64, xp);
    __syncthreads();                       // initial: bufX[0] visible

    #pragma unroll 1
    for (int g = 0; g < 8; ++g) {
        const int vg = vbase + g * 64;

        // hoist this group's segment ids (latency overlaps L1/L2 compute)
        int sgv[4];
        #pragma unroll
        for (int nt = 0; nt < 4; ++nt) sgv[nt] = idx[vg + nt * 16 + l15];

        // ---- layer 1 (K=32): bufX[g&1] -> act1, bias in C, relu ----
        const u16* bx = bufX[g & 1];
        #pragma unroll
        for (int nt = 0; nt < 4; ++nt) {
            int vr = nt * 16 + l15;
            union { bf16x8 v; short4v h[2]; } b;
            b.h[0] = *(const short4v*)(bx + vr * XSTR + qd * 8);
            b.h[1] = *(const short4v*)(bx + vr * XSTR + qd * 8 + 4);
            u16* wr = act1 + vr * ASTR + f0 + qd * 4;
            #pragma unroll
            for (int mt = 0; mt < 2; ++mt) {
                f32x4 a = __builtin_amdgcn_mfma_f32_16x16x32_bf16(w1a[mt], b.v, b1f[mt], 0, 0, 0);
                uint2 s;
                s.x = pkbf(fmaxf(a[0], 0.f), fmaxf(a[1], 0.f));
                s.y = pkbf(fmaxf(a[2], 0.f), fmaxf(a[3], 0.f));
                *(uint2*)(wr + mt * 16) = s;
            }
        }
        __syncthreads();                   // B_b: act1 visible

        // ---- stage bufX for g+1 from regs; refill regs for g+2 ----
        if (g < 7) stagex(bufX[(g + 1) & 1], xp);
        if (g < 6) loadx(vg + 128, xp);

        // ---- layer 2 (K=128): act1 -> act2, bias in C, relu ----
        #pragma unroll
        for (int nt = 0; nt < 4; ++nt) {
            const u16* rd = act1 + (nt * 16 + l15) * ASTR + qd * 8;
            bf16x8 B2[4];
            #pragma unroll
            for (int kk = 0; kk < 4; ++kk) B2[kk] = *(const bf16x8*)(rd + kk * 32);
            u16* wr = act2 + (nt * 16 + l15) * ASTR + f0 + qd * 4;
            #pragma unroll
            for (int mt = 0; mt < 2; ++mt) {
                f32x4 a = b2f[mt];
                #pragma unroll
                for (int kk = 0; kk < 4; ++kk)
                    a = __builtin_amdgcn_mfma_f32_16x16x32_bf16(w2a[mt][kk], B2[kk], a, 0, 0, 0);
                uint2 s;
                s.x = pkbf(fmaxf(a[0], 0.f), fmaxf(a[1], 0.f));
                s.y = pkbf(fmaxf(a[2], 0.f), fmaxf(a[3], 0.f));
                *(uint2*)(wr + mt * 16) = s;
            }
        }
        __syncthreads();                   // B_c: act2 AND bufX[(g+1)&1] visible

        // ---- layer 3 (K=128): act2 -> accR via C-chaining ----
        #pragma unroll 1
        for (int nt = 0; nt < 4; ++nt) {
            int sg = sgv[nt];
            const u16* rd = act2 + (nt * 16 + l15) * ASTR + qd * 8;
            bf16x8 B3[4];
            #pragma unroll
            for (int kk = 0; kk < 4; ++kk) B3[kk] = *(const bf16x8*)(rd + kk * 32);
            int first = __builtin_amdgcn_readfirstlane(sg);
            bool uni = (__ballot(sg == first) == ~0ull);
            if (uni) {
                if (first != cur) {
                    if (cntv > 0.f) flush();
                    cur = first;
                }
                #pragma unroll
                for (int mt = 0; mt < 2; ++mt) {
                    f32x4 a = accR[mt];
                    #pragma unroll
                    for (int kk = 0; kk < 4; ++kk)
                        a = __builtin_amdgcn_mfma_f32_16x16x32_bf16(w3a[mt][kk], B3[kk], a, 0, 0, 0);
                    accR[mt] = a;
                }
                cntv += 16.f;
            } else {                       // boundary inside subtile (rare)
                if (cntv > 0.f) flush();
                f32x4 D[2];
                #pragma unroll
                for (int mt = 0; mt < 2; ++mt) {
                    f32x4 a = {0.f, 0.f, 0.f, 0.f};
                    #pragma unroll
                    for (int kk = 0; kk < 4; ++kk)
                        a = __builtin_amdgcn_mfma_f32_16x16x32_bf16(w3a[mt][kk], B3[kk], a, 0, 0, 0);
                    D[mt] = a;
                }
                // segmented inclusive scan over 16 voter lanes (sorted -> masking safe)
                float one = 1.f;
                #pragma unroll
                for (int d = 1; d < 16; d <<= 1) {
                    int so = __shfl_up(sg, d, 16);
                    bool ok = (l15 >= d) && (so == sg);
                    #pragma unroll
                    for (int mt = 0; mt < 2; ++mt)
                        #pragma unroll
                        for (int r = 0; r < 4; ++r) {
                            float o = __shfl_up(D[mt][r], d, 16);
                            if (ok) D[mt][r] += o;
                        }
                    float oc = __shfl_up(one, d, 16);
                    if (ok) one += oc;
                }
                int sgn = __shfl_down(sg, 1, 16);
                bool isend = (l15 == 15) || (sgn != sg);
                if (isend) {
                    float* p = agg + (size_t)sg * EMB + f0 + qd * 4;
                    #pragma unroll
                    for (int mt = 0; mt < 2; ++mt)
                        #pragma unroll
                        for (int r = 0; r < 4; ++r) atomicAdd(p + mt * 16 + r, D[mt][r]);
                    if (wv == 0 && qd == 0) atomicAdd(cntf + sg, one);
                }
                cur = __shfl(sg, 15, 16);  // last voter's run continues
            }
        }
    }
    if (cntv > 0.f) flush();
}

// ---------------- Kernel C: global MLP + log_softmax (fp32) ----------------
// Adds deferred local bias3: agg_true[s][j] = agg[s][j] + cnt[s]*lb3[j].
__global__ __launch_bounds__(256) void global_mlp(
    const float* __restrict__ agg, const float* __restrict__ cntf, const float* __restrict__ lb3,
    const float* __restrict__ gW1, const float* __restrict__ gb1,
    const float* __restrict__ gW2, const float* __restrict__ gb2,
    const float* __restrict__ gW3, const float* __restrict__ gb3,
    float* __restrict__ out)
{
    __shared__ float actA[8 * 128];
    __shared__ float actB[8 * 128];
    __shared__ float sc[8 * 32];
    const int tid = threadIdx.x;
    const int s0 = blockIdx.x * 8;

    #pragma unroll
    for (int i = 0; i < 4; ++i) {
        int f = i * 256 + tid;
        actA[f] = agg[(size_t)s0 * 128 + f] + cntf[s0 + (f >> 7)] * lb3[f & 127];
    }
    __syncthreads();

    const int j = tid & 127, g = tid >> 7;
    {
        float acc[4];
        #pragma unroll
        for (int si = 0; si < 4; ++si) acc[si] = gb1[j];
        #pragma unroll 8
        for (int k = 0; k < 128; ++k) {
            float w = gW1[k * 128 + j];
            #pragma unroll
            for (int si = 0; si < 4; ++si) acc[si] += actA[(g * 4 + si) * 128 + k] * w;
        }
        #pragma unroll
        for (int si = 0; si < 4; ++si) actB[(g * 4 + si) * 128 + j] = fmaxf(acc[si], 0.f);
    }
    __syncthreads();
    {
        float acc[4];
        #pragma unroll
        for (int si = 0; si < 4; ++si) acc[si] = gb2[j];
        #pragma unroll 8
        for (int k = 0; k < 128; ++k) {
            float w = gW2[k * 128 + j];
            #pragma unroll
            for (int si = 0; si < 4; ++si) acc[si] += actB[(g * 4 + si) * 128 + k] * w;
        }
        #pragma unroll
        for (int si = 0; si < 4; ++si) actA[(g * 4 + si) * 128 + j] = fmaxf(acc[si], 0.f);
    }
    __syncthreads();
    {
        int c = tid & 31, sg = tid >> 5;
        float a3 = gb3[c];
        #pragma unroll 8
        for (int k = 0; k < 128; ++k) a3 += actA[sg * 128 + k] * gW3[k * 32 + c];
        sc[sg * 32 + c] = a3;
    }
    __syncthreads();
    {
        int c = tid & 31, sg = tid >> 5;
        float v = sc[sg * 32 + c];
        float m = v;
        #pragma unroll
        for (int off = 16; off >= 1; off >>= 1) m = fmaxf(m, __shfl_xor(m, off, 32));
        float e = expf(v - m);
        float sum = e;
        #pragma unroll
        for (int off = 16; off >= 1; off >>= 1) sum += __shfl_xor(sum, off, 32);
        out[(size_t)(s0 + sg) * 32 + c] = (v - m) - logf(sum);
    }
}

extern "C" void kernel_launch(void* const* d_in, const int* in_sizes, int n_in,
                              void* d_out, int out_size, void* d_ws, size_t ws_size,
                              hipStream_t stream) {
    const float* x   = (const float*)d_in[0];
    const int*   idx = (const int*)d_in[1];
    const float* lW1 = (const float*)d_in[2];
    const float* lb1 = (const float*)d_in[3];
    const float* lW2 = (const float*)d_in[4];
    const float* lb2 = (const float*)d_in[5];
    const float* lW3 = (const float*)d_in[6];
    const float* lb3 = (const float*)d_in[7];
    const float* gW1 = (const float*)d_in[8];
    const float* gb1 = (const float*)d_in[9];
    const float* gW2 = (const float*)d_in[10];
    const float* gb2 = (const float*)d_in[11];
    const float* gW3 = (const float*)d_in[12];
    const float* gb3 = (const float*)d_in[13];
    float* out = (float*)d_out;

    float* agg  = (float*)d_ws;                                 // [4096][128] fp32 = 2 MB
    float* cntf = agg + (size_t)NUM_ELEC * EMB;                 // [4096] fp32
    u16* w1t = (u16*)(cntf + NUM_ELEC);
    u16* w2t = w1t + 128 * 32;
    u16* w3t = w2t + 128 * 128;

    hipMemsetAsync(d_ws, 0, ((size_t)NUM_ELEC * EMB + NUM_ELEC) * sizeof(float), stream);
    prep_weights<<<64, 256, 0, stream>>>(lW1, lW2, lW3, w1t, w2t, w3t);
    local_fused<<<N_VOTERS / 512, 256, 0, stream>>>(x, idx, lb1, lb2, w1t, w2t, w3t, agg, cntf);
    global_mlp<<<NUM_ELEC / 8, 256, 0, stream>>>(agg, cntf, lb3, gW1, gb1, gW2, gb2, gW3, gb3, out);
}

// Round 11
// 299.700 us; speedup vs baseline: 1.3591x; 1.0054x over previous
//
#include <hip/hip_runtime.h>
#include <hip/hip_bf16.h>
#include <math.h>

#define N_VOTERS 1048576
#define NUM_CAND 32
#define EMB 128
#define NUM_ELEC 4096

typedef unsigned short u16;
typedef unsigned int u32;
typedef __attribute__((ext_vector_type(8))) short bf16x8;
typedef __attribute__((ext_vector_type(4))) short short4v;
typedef __attribute__((ext_vector_type(4))) float f32x4;

#if defined(__has_builtin)
#if __has_builtin(__builtin_amdgcn_cvt_pk_bf16_f32)
#define HAVE_CVT_PK_BF16 1
#endif
#endif

__device__ __forceinline__ u16 f2bf(float f) {   // RNE (prep only)
    union { float f; u32 u; } v; v.f = f;
    u32 r = v.u + 0x7FFFu + ((v.u >> 16) & 1u);
    return (u16)(r >> 16);
}
// pack two floats to bf16: f0 -> low16, f1 -> high16.
// Fast path: single v_cvt_pk_bf16_f32 (RNE). Fallback: add+add+perm (round-half-up).
__device__ __forceinline__ u32 pk2(float f0, float f1) {
#ifdef HAVE_CVT_PK_BF16
    typedef __attribute__((ext_vector_type(2))) __bf16 bf16x2;
    bf16x2 r = __builtin_amdgcn_cvt_pk_bf16_f32(f0, f1);   // lo=cvt(f0), hi=cvt(f1)
    union { bf16x2 v; u32 u; } c; c.v = r;
    return c.u;
#else
    u32 u0 = __float_as_uint(f0) + 0x8000u;
    u32 u1 = __float_as_uint(f1) + 0x8000u;
    return __builtin_amdgcn_perm(u1, u0, 0x07060302u);
#endif
}

// ---------------- Kernel A: transpose+convert local weights to bf16 ----------------
// w1t: [128][32] = W1^T (out-major); w2t/w3t: [128][128] (out-major) — A-frag layout.
__global__ void prep_weights(const float* __restrict__ lW1, const float* __restrict__ lW2,
                             const float* __restrict__ lW3,
                             u16* __restrict__ w1t, u16* __restrict__ w2t, u16* __restrict__ w3t) {
    int tid = blockIdx.x * blockDim.x + threadIdx.x;  // 0..16383
    if (tid < 4096) {
        int n = tid >> 5, k = tid & 31;
        w1t[tid] = f2bf(lW1[k * EMB + n]);
    }
    {
        int n = tid >> 7, k = tid & 127;
        w2t[tid] = f2bf(lW2[k * EMB + n]);
        w3t[tid] = f2bf(lW3[k * EMB + n]);
    }
}

// ---------------- Kernel B: fused local MLP, grid-stride groups, resident weights -------
// 2048 blocks x 256 thr (4 waves). Wave wv owns features wv*32..+31 (2 m-tiles); weights +
// biases loaded ONCE per block into VGPRs (needs the >=160-VGPR budget of
// __launch_bounds__(256,3) — at (256,4) the compiler REMATERIALIZES weight loads per group:
// R9 measured FETCH 68->371 MB, 155->226 us. Do not tighten).
// 8 groups x 64 voters. bufX is DOUBLE-BUFFERED: group g's L2 phase stages bufX for g+1
// from registers prefetched in group g-1, so the act2 barrier also publishes bufX ->
// 2 barriers/group (R10: 155->122 us vs 3 barriers). Bias1/2 ride the MFMA C operand.
// Layer-3 C-operand chains the segment sum across subtiles AND groups; flush = butterfly
// over 16 voter lanes + l15==0 atomics. Bias3 deferred via per-election voter counts.
// NOTE: SQ_LDS_BANK_CONFLICT ~13.1M is the arithmetic floor of b64/b128 multi-phase
// access (64 lanes x 2/4 dwords over 32 banks) — not a lever.
__global__ __launch_bounds__(256, 3) void local_fused(
    const float* __restrict__ x, const int* __restrict__ idx,
    const float* __restrict__ lb1, const float* __restrict__ lb2,
    const u16* __restrict__ w1t, const u16* __restrict__ w2t, const u16* __restrict__ w3t,
    float* __restrict__ agg, float* __restrict__ cntf)
{
    constexpr int XSTR = 36;   // x tile stride (72B rows, 8B-aligned b64 reads)
    constexpr int ASTR = 136;  // act stride (272B rows, 16B-aligned b128 reads)
    __shared__ __align__(16) u16 bufX[2][64 * XSTR];  // 2 x 4608 B
    __shared__ __align__(16) u16 act1[64 * ASTR];     // 17408 B
    __shared__ __align__(16) u16 act2[64 * ASTR];     // 17408 B  (total 44032)

    const int tid = threadIdx.x;
    const int lane = tid & 63;
    const int wv = tid >> 6;        // feature quarter 0..3
    const int qd = lane >> 4;
    const int l15 = lane & 15;
    const int f0 = wv * 32;
    const int vbase = blockIdx.x * 512;

    // ---- weights + biases resident for the whole block ----
    bf16x8 w1a[2], w2a[2][4], w3a[2][4];
    f32x4 b1f[2], b2f[2];
    #pragma unroll
    for (int mt = 0; mt < 2; ++mt) {
        int mrow = f0 + mt * 16 + l15;
        w1a[mt] = *(const bf16x8*)(w1t + mrow * 32 + qd * 8);
        #pragma unroll
        for (int kk = 0; kk < 4; ++kk) {
            w2a[mt][kk] = *(const bf16x8*)(w2t + mrow * 128 + kk * 32 + qd * 8);
            w3a[mt][kk] = *(const bf16x8*)(w3t + mrow * 128 + kk * 32 + qd * 8);
        }
        b1f[mt] = *(const f32x4*)(lb1 + f0 + mt * 16 + qd * 4);
        b2f[mt] = *(const f32x4*)(lb2 + f0 + mt * 16 + qd * 4);
    }

    // ---- segment state (spans all 8 groups) ----
    f32x4 accR[2];
    #pragma unroll
    for (int mt = 0; mt < 2; ++mt) accR[mt] = (f32x4){0.f, 0.f, 0.f, 0.f};
    float cntv = 0.f;
    int cur = idx[vbase];

    auto flush = [&]() {   // wave-uniform call sites only
        #pragma unroll
        for (int d = 1; d < 16; d <<= 1)
            #pragma unroll
            for (int mt = 0; mt < 2; ++mt)
                #pragma unroll
                for (int r = 0; r < 4; ++r) accR[mt][r] += __shfl_xor(accR[mt][r], d, 16);
        if (l15 == 0) {
            float* p = agg + (size_t)cur * EMB + f0 + qd * 4;
            #pragma unroll
            for (int mt = 0; mt < 2; ++mt)
                #pragma unroll
                for (int r = 0; r < 4; ++r) atomicAdd(p + mt * 16 + r, accR[mt][r]);
            if (wv == 0 && qd == 0) atomicAdd(cntf + cur, cntv);
        }
        #pragma unroll
        for (int mt = 0; mt < 2; ++mt) accR[mt] = (f32x4){0.f, 0.f, 0.f, 0.f};
        cntv = 0.f;
    };

    auto loadx = [&](int v0, uint2* xp) {   // coalesced read + pack of one 64-voter tile
        const float4* xg = (const float4*)(x + (size_t)v0 * NUM_CAND);
        #pragma unroll
        for (int i = 0; i < 2; ++i) {
            float4 v = xg[i * 256 + tid];
            xp[i].x = pk2(v.x, v.y); xp[i].y = pk2(v.z, v.w);
        }
    };
    auto stagex = [&](u16* dst, const uint2* xp) {
        #pragma unroll
        for (int i = 0; i < 2; ++i) {
            int F = i * 256 + tid, row = F >> 3, c4 = (F & 7) * 4;
            *(uint2*)(dst + row * XSTR + c4) = xp[i];
        }
    };

    // ---- prologue: stage group 0, prefetch group 1 into regs ----
    uint2 xp[2];
    loadx(vbase, xp);
    stagex(bufX[0], xp);
    loadx(vbase + 64, xp);
    __syncthreads();                       // initial: bufX[0] visible

    #pragma unroll 1
    for (int g = 0; g < 8; ++g) {
        const int vg = vbase + g * 64;

        // hoist this group's segment ids (latency overlaps L1/L2 compute)
        int sgv[4];
        #pragma unroll
        for (int nt = 0; nt < 4; ++nt) sgv[nt] = idx[vg + nt * 16 + l15];

        // ---- layer 1 (K=32): bufX[g&1] -> act1, bias in C, relu ----
        const u16* bx = bufX[g & 1];
        #pragma unroll
        for (int nt = 0; nt < 4; ++nt) {
            int vr = nt * 16 + l15;
            union { bf16x8 v; short4v h[2]; } b;
            b.h[0] = *(const short4v*)(bx + vr * XSTR + qd * 8);
            b.h[1] = *(const short4v*)(bx + vr * XSTR + qd * 8 + 4);
            u16* wr = act1 + vr * ASTR + f0 + qd * 4;
            #pragma unroll
            for (int mt = 0; mt < 2; ++mt) {
                f32x4 a = __builtin_amdgcn_mfma_f32_16x16x32_bf16(w1a[mt], b.v, b1f[mt], 0, 0, 0);
                uint2 s;
                s.x = pk2(fmaxf(a[0], 0.f), fmaxf(a[1], 0.f));
                s.y = pk2(fmaxf(a[2], 0.f), fmaxf(a[3], 0.f));
                *(uint2*)(wr + mt * 16) = s;
            }
        }
        __syncthreads();                   // B_b: act1 visible

        // ---- stage bufX for g+1 from regs; refill regs for g+2 ----
        if (g < 7) stagex(bufX[(g + 1) & 1], xp);
        if (g < 6) loadx(vg + 128, xp);

        // ---- layer 2 (K=128): act1 -> act2, bias in C, relu ----
        #pragma unroll
        for (int nt = 0; nt < 4; ++nt) {
            const u16* rd = act1 + (nt * 16 + l15) * ASTR + qd * 8;
            bf16x8 B2[4];
            #pragma unroll
            for (int kk = 0; kk < 4; ++kk) B2[kk] = *(const bf16x8*)(rd + kk * 32);
            u16* wr = act2 + (nt * 16 + l15) * ASTR + f0 + qd * 4;
            #pragma unroll
            for (int mt = 0; mt < 2; ++mt) {
                f32x4 a = b2f[mt];
                #pragma unroll
                for (int kk = 0; kk < 4; ++kk)
                    a = __builtin_amdgcn_mfma_f32_16x16x32_bf16(w2a[mt][kk], B2[kk], a, 0, 0, 0);
                uint2 s;
                s.x = pk2(fmaxf(a[0], 0.f), fmaxf(a[1], 0.f));
                s.y = pk2(fmaxf(a[2], 0.f), fmaxf(a[3], 0.f));
                *(uint2*)(wr + mt * 16) = s;
            }
        }
        __syncthreads();                   // B_c: act2 AND bufX[(g+1)&1] visible

        // ---- layer 3 (K=128): act2 -> accR via C-chaining ----
        #pragma unroll 1
        for (int nt = 0; nt < 4; ++nt) {
            int sg = sgv[nt];
            const u16* rd = act2 + (nt * 16 + l15) * ASTR + qd * 8;
            bf16x8 B3[4];
            #pragma unroll
            for (int kk = 0; kk < 4; ++kk) B3[kk] = *(const bf16x8*)(rd + kk * 32);
            int first = __builtin_amdgcn_readfirstlane(sg);
            bool uni = (__ballot(sg == first) == ~0ull);
            if (uni) {
                if (first != cur) {
                    if (cntv > 0.f) flush();
                    cur = first;
                }
                #pragma unroll
                for (int mt = 0; mt < 2; ++mt) {
                    f32x4 a = accR[mt];
                    #pragma unroll
                    for (int kk = 0; kk < 4; ++kk)
                        a = __builtin_amdgcn_mfma_f32_16x16x32_bf16(w3a[mt][kk], B3[kk], a, 0, 0, 0);
                    accR[mt] = a;
                }
                cntv += 16.f;
            } else {                       // boundary inside subtile (rare)
                if (cntv > 0.f) flush();
                f32x4 D[2];
                #pragma unroll
                for (int mt = 0; mt < 2; ++mt) {
                    f32x4 a = {0.f, 0.f, 0.f, 0.f};
                    #pragma unroll
                    for (int kk = 0; kk < 4; ++kk)
                        a = __builtin_amdgcn_mfma_f32_16x16x32_bf16(w3a[mt][kk], B3[kk], a, 0, 0, 0);
                    D[mt] = a;
                }
                // segmented inclusive scan over 16 voter lanes (sorted -> masking safe)
                float one = 1.f;
                #pragma unroll
                for (int d = 1; d < 16; d <<= 1) {
                    int so = __shfl_up(sg, d, 16);
                    bool ok = (l15 >= d) && (so == sg);
                    #pragma unroll
                    for (int mt = 0; mt < 2; ++mt)
                        #pragma unroll
                        for (int r = 0; r < 4; ++r) {
                            float o = __shfl_up(D[mt][r], d, 16);
                            if (ok) D[mt][r] += o;
                        }
                    float oc = __shfl_up(one, d, 16);
                    if (ok) one += oc;
                }
                int sgn = __shfl_down(sg, 1, 16);
                bool isend = (l15 == 15) || (sgn != sg);
                if (isend) {
                    float* p = agg + (size_t)sg * EMB + f0 + qd * 4;
                    #pragma unroll
                    for (int mt = 0; mt < 2; ++mt)
                        #pragma unroll
                        for (int r = 0; r < 4; ++r) atomicAdd(p + mt * 16 + r, D[mt][r]);
                    if (wv == 0 && qd == 0) atomicAdd(cntf + sg, one);
                }
                cur = __shfl(sg, 15, 16);  // last voter's run continues
            }
        }
    }
    if (cntv > 0.f) flush();
}

// ---------------- Kernel C: global MLP + log_softmax (fp32) ----------------
// Adds deferred local bias3: agg_true[s][j] = agg[s][j] + cnt[s]*lb3[j].
__global__ __launch_bounds__(256) void global_mlp(
    const float* __restrict__ agg, const float* __restrict__ cntf, const float* __restrict__ lb3,
    const float* __restrict__ gW1, const float* __restrict__ gb1,
    const float* __restrict__ gW2, const float* __restrict__ gb2,
    const float* __restrict__ gW3, const float* __restrict__ gb3,
    float* __restrict__ out)
{
    __shared__ float actA[8 * 128];
    __shared__ float actB[8 * 128];
    __shared__ float sc[8 * 32];
    const int tid = threadIdx.x;
    const int s0 = blockIdx.x * 8;

    #pragma unroll
    for (int i = 0; i < 4; ++i) {
        int f = i * 256 + tid;
        actA[f] = agg[(size_t)s0 * 128 + f] + cntf[s0 + (f >> 7)] * lb3[f & 127];
    }
    __syncthreads();

    const int j = tid & 127, g = tid >> 7;
    {
        float acc[4];
        #pragma unroll
        for (int si = 0; si < 4; ++si) acc[si] = gb1[j];
        #pragma unroll 8
        for (int k = 0; k < 128; ++k) {
            float w = gW1[k * 128 + j];
            #pragma unroll
            for (int si = 0; si < 4; ++si) acc[si] += actA[(g * 4 + si) * 128 + k] * w;
        }
        #pragma unroll
        for (int si = 0; si < 4; ++si) actB[(g * 4 + si) * 128 + j] = fmaxf(acc[si], 0.f);
    }
    __syncthreads();
    {
        float acc[4];
        #pragma unroll
        for (int si = 0; si < 4; ++si) acc[si] = gb2[j];
        #pragma unroll 8
        for (int k = 0; k < 128; ++k) {
            float w = gW2[k * 128 + j];
            #pragma unroll
            for (int si = 0; si < 4; ++si) acc[si] += actB[(g * 4 + si) * 128 + k] * w;
        }
        #pragma unroll
        for (int si = 0; si < 4; ++si) actA[(g * 4 + si) * 128 + j] = fmaxf(acc[si], 0.f);
    }
    __syncthreads();
    {
        int c = tid & 31, sg = tid >> 5;
        float a3 = gb3[c];
        #pragma unroll 8
        for (int k = 0; k < 128; ++k) a3 += actA[sg * 128 + k] * gW3[k * 32 + c];
        sc[sg * 32 + c] = a3;
    }
    __syncthreads();
    {
        int c = tid & 31, sg = tid >> 5;
        float v = sc[sg * 32 + c];
        float m = v;
        #pragma unroll
        for (int off = 16; off >= 1; off >>= 1) m = fmaxf(m, __shfl_xor(m, off, 32));
        float e = expf(v - m);
        float sum = e;
        #pragma unroll
        for (int off = 16; off >= 1; off >>= 1) sum += __shfl_xor(sum, off, 32);
        out[(size_t)(s0 + sg) * 32 + c] = (v - m) - logf(sum);
    }
}

extern "C" void kernel_launch(void* const* d_in, const int* in_sizes, int n_in,
                              void* d_out, int out_size, void* d_ws, size_t ws_size,
                              hipStream_t stream) {
    const float* x   = (const float*)d_in[0];
    const int*   idx = (const int*)d_in[1];
    const float* lW1 = (const float*)d_in[2];
    const float* lb1 = (const float*)d_in[3];
    const float* lW2 = (const float*)d_in[4];
    const float* lb2 = (const float*)d_in[5];
    const float* lW3 = (const float*)d_in[6];
    const float* lb3 = (const float*)d_in[7];
    const float* gW1 = (const float*)d_in[8];
    const float* gb1 = (const float*)d_in[9];
    const float* gW2 = (const float*)d_in[10];
    const float* gb2 = (const float*)d_in[11];
    const float* gW3 = (const float*)d_in[12];
    const float* gb3 = (const float*)d_in[13];
    float* out = (float*)d_out;

    float* agg  = (float*)d_ws;                                 // [4096][128] fp32 = 2 MB
    float* cntf = agg + (size_t)NUM_ELEC * EMB;                 // [4096] fp32
    u16* w1t = (u16*)(cntf + NUM_ELEC);
    u16* w2t = w1t + 128 * 32;
    u16* w3t = w2t + 128 * 128;

    hipMemsetAsync(d_ws, 0, ((size_t)NUM_ELEC * EMB + NUM_ELEC) * sizeof(float), stream);
    prep_weights<<<64, 256, 0, stream>>>(lW1, lW2, lW3, w1t, w2t, w3t);
    local_fused<<<N_VOTERS / 512, 256, 0, stream>>>(x, idx, lb1, lb2, w1t, w2t, w3t, agg, cntf);
    global_mlp<<<NUM_ELEC / 8, 256, 0, stream>>>(agg, cntf, lb3, gW1, gb1, gW2, gb2, gW3, gb3, out);
}